// Round 14
// baseline (2209.734 us; speedup 1.0000x reference)
//
#include <hip/hip_runtime.h>
#include <hip/hip_bf16.h>

// ---------------------------------------------------------------------------
// GCN: h = relu(GCNConv(x,W1,b1)); x1 = relu(GCNConv(h,W2,b2));
//      x2 = meanpool(x1,batch); out = log_softmax(relu(x2@fc1+b)@fc2+b)
//
// R14: bucket CSR deleted. Edges partitioned into ranges of 96 dst nodes
// (rangecnt -> 521-wide scan -> partplace); aggregation = scatter-into-LDS
// (96x64 fp32 acc per block, ds_add_f32, conflict-free 2-lane/bank), one
// block per (range, slice). Replaces hist2+scan2+place2+slot (~55us) with
// ~12us of range kernels. Pool fused into layer-2 scatter epilogue (sorted
// batch -> <=4 graphs/range in LDS); x1 never materialized. MFMA GEMMs and
// fp8 tables unchanged from R13.
// ---------------------------------------------------------------------------

#define NPR 96       // dst nodes per range (LDS acc = 96*64 f32 = 24.5KB)
#define RMAX 1024    // max ranges (N <= 98304)
#define KP 136       // bf16 weight row stride (128 + 8 pad)

typedef float v2f  __attribute__((ext_vector_type(2)));
typedef float f32x4 __attribute__((ext_vector_type(4)));
typedef short bf16x8 __attribute__((ext_vector_type(8)));

__device__ inline unsigned short f2bf(float f) {   // fp32 -> bf16 RNE
    unsigned u = __float_as_uint(f);
    u += 0x7FFFu + ((u >> 16) & 1u);
    return (unsigned short)(u >> 16);
}
__device__ inline unsigned f32x4_to_fp8(float a, float b, float c, float d) {
    int w = 0;
    w = __builtin_amdgcn_cvt_pk_fp8_f32(a, b, w, false);
    w = __builtin_amdgcn_cvt_pk_fp8_f32(c, d, w, true);
    return (unsigned)w;
}

// Weight prep: wt[c][k] (bf16, stride KP) = W[k][c].  Block 0 -> W1, 1 -> W2.
__global__ void prepw_kernel(const float* __restrict__ W1, const float* __restrict__ W2,
                             unsigned short* __restrict__ wt1, unsigned short* __restrict__ wt2) {
    int t = threadIdx.x;
    if (blockIdx.x == 0) {
        for (int i = t; i < 128 * 128; i += 256) {
            int c = i >> 7, k = i & 127;
            wt1[c * KP + k] = f2bf(W1[k * 128 + c]);
        }
    } else {
        for (int i = t; i < 64 * 128; i += 256) {
            int c = i >> 7, k = i & 127;
            wt2[c * KP + k] = f2bf(W2[k * 64 + c]);
        }
    }
}

// C1: per-block LDS histogram of cols -> ranges, merged into global rangeCnt.
__global__ void rangecnt_kernel(const int* __restrict__ cols, int* __restrict__ rangeCnt,
                                int E, int NRANGES) {
    __shared__ int rc[RMAX];
    const int t = threadIdx.x;
    const int CS = (E + gridDim.x - 1) / gridDim.x;
    const int e0 = blockIdx.x * CS, e1 = min(e0 + CS, E);
    for (int i = t; i < NRANGES; i += 256) rc[i] = 0;
    __syncthreads();
    for (int e = e0 + t; e < e1; e += 256) atomicAdd(&rc[cols[e] / NPR], 1);
    __syncthreads();
    for (int i = t; i < NRANGES; i += 256) if (rc[i]) atomicAdd(&rangeCnt[i], rc[i]);
}

// C2: exclusive scan over NRANGES (<=1024) -> rangeBase[+1], rangeCur copy.
__global__ __launch_bounds__(1024)
void rangescan_kernel(const int* __restrict__ rangeCnt, int* __restrict__ rangeBase,
                      int* __restrict__ rangeCur, int NRANGES) {
    __shared__ int part[1024];
    const int t = threadIdx.x;
    int v = (t < NRANGES) ? rangeCnt[t] : 0;
    part[t] = v;
    __syncthreads();
    for (int off = 1; off < 1024; off <<= 1) {
        int add = (t >= off) ? part[t - off] : 0;
        __syncthreads();
        part[t] += add;
        __syncthreads();
    }
    int ex = part[t] - v;
    if (t < NRANGES) { rangeBase[t] = ex; rangeCur[t] = ex; }
    if (t == 1023) rangeBase[NRANGES] = part[1023];
}

// C3: write edges into per-range segments: rng[pos] = (col, row<<15|q15(ew)).
__global__ void partplace_kernel(const int* __restrict__ rows, const int* __restrict__ cols,
                                 const float* __restrict__ ew, int* __restrict__ rangeCur,
                                 uint2* __restrict__ rng, int E, int NRANGES) {
    __shared__ int cur[RMAX];
    const int t = threadIdx.x;
    const int CS = (E + gridDim.x - 1) / gridDim.x;
    const int e0 = blockIdx.x * CS, e1 = min(e0 + CS, E);
    for (int i = t; i < NRANGES; i += 256) cur[i] = 0;
    __syncthreads();
    for (int e = e0 + t; e < e1; e += 256) atomicAdd(&cur[cols[e] / NPR], 1);
    __syncthreads();
    for (int i = t; i < NRANGES; i += 256) if (cur[i]) cur[i] = atomicAdd(&rangeCur[i], cur[i]);
    __syncthreads();
    for (int e = e0 + t; e < e1; e += 256) {
        int c = cols[e];
        int q = (int)(ew[e] * 32768.0f);
        if (q > 32767) q = 32767;
        int pos = atomicAdd(&cur[c / NPR], 1);
        rng[pos] = make_uint2((unsigned)c, ((unsigned)rows[e] << 15) | (unsigned)q);
    }
}

// C4: per-range weight sums -> dinv (LDS int accumulation, no global atomics).
__global__ void degr_kernel(const uint2* __restrict__ rng, const int* __restrict__ rangeBase,
                            float* __restrict__ dinv, int N) {
    __shared__ int wsum[NPR];
    const int r = blockIdx.x, t = threadIdx.x;
    for (int i = t; i < NPR; i += 256) wsum[i] = 0;
    __syncthreads();
    const int e0 = rangeBase[r], e1 = rangeBase[r + 1];
    for (int e = e0 + t; e < e1; e += 256) {
        uint2 u = rng[e];
        atomicAdd(&wsum[u.x - r * NPR], (int)(u.y & 32767u));
    }
    __syncthreads();
    for (int i = t; i < NPR; i += 256) {
        int node = r * NPR + i;
        if (node < N) dinv[node] = rsqrtf((float)wsum[i] * (1.0f / 32768.0f) + 1.0f);
    }
}

// MFMA bf16 GEMM -> fp8 sliced table. outf8[slice][M][64] = (A@W)*dinv[row].
// (R13-verified fragment layouts.)
template <int BN, bool AF32>
__global__ __launch_bounds__(256)
void gemm_mfma_kernel(const void* __restrict__ Av, const unsigned short* __restrict__ wt,
                      const float* __restrict__ dinv, unsigned char* __restrict__ outf8,
                      int M) {
    constexpr int CT = BN / 16;
    constexpr int EPS = BN + 4;
    __shared__ unsigned short wl[BN * KP];
    __shared__ float ep[4][16 * EPS];
    const int t = threadIdx.x;
    for (int i = t; i < BN * KP / 8; i += 256)
        ((uint4*)wl)[i] = ((const uint4*)wt)[i];
    __syncthreads();
    const int w = t >> 6, lane = t & 63;
    const int n16 = lane & 15, q = lane >> 4;
    const int rowBase = blockIdx.x * 64 + w * 16;
    int arow = rowBase + n16; if (arow >= M) arow = M - 1;
    f32x4 acc[CT];
    #pragma unroll
    for (int ct = 0; ct < CT; ++ct) acc[ct] = (f32x4){0.f, 0.f, 0.f, 0.f};
    #pragma unroll
    for (int kt = 0; kt < 4; ++kt) {
        bf16x8 af;
        if (AF32) {
            const float* ap = (const float*)Av + (size_t)arow * 128 + kt * 32 + q * 8;
            float4 a0 = *(const float4*)ap;
            float4 a1 = *(const float4*)(ap + 4);
            af[0] = (short)f2bf(a0.x); af[1] = (short)f2bf(a0.y);
            af[2] = (short)f2bf(a0.z); af[3] = (short)f2bf(a0.w);
            af[4] = (short)f2bf(a1.x); af[5] = (short)f2bf(a1.y);
            af[6] = (short)f2bf(a1.z); af[7] = (short)f2bf(a1.w);
        } else {
            af = *(const bf16x8*)((const unsigned short*)Av + (size_t)arow * 128 + kt * 32 + q * 8);
        }
        #pragma unroll
        for (int ct = 0; ct < CT; ++ct) {
            bf16x8 bfr = *(const bf16x8*)&wl[(ct * 16 + n16) * KP + kt * 32 + q * 8];
            acc[ct] = __builtin_amdgcn_mfma_f32_16x16x32_bf16(af, bfr, acc[ct], 0, 0, 0);
        }
    }
    #pragma unroll
    for (int ct = 0; ct < CT; ++ct)
        #pragma unroll
        for (int r = 0; r < 4; ++r)
            ep[w][(q * 4 + r) * EPS + ct * 16 + n16] = acc[ct][r];
    __syncthreads();
    const int lr = lane & 15;
    const int cc = (lane >> 4) * (BN / 4);
    int grow = rowBase + lr;
    if (grow < M) {
        float s = dinv[grow];
        const float* src = &ep[w][lr * EPS + cc];
        #pragma unroll
        for (int u = 0; u < BN / 64; ++u) {
            int col0 = cc + u * 16;
            int slice = col0 >> 6, cw = col0 & 63;
            unsigned w0 = f32x4_to_fp8(src[u*16+ 0]*s, src[u*16+ 1]*s, src[u*16+ 2]*s, src[u*16+ 3]*s);
            unsigned w1 = f32x4_to_fp8(src[u*16+ 4]*s, src[u*16+ 5]*s, src[u*16+ 6]*s, src[u*16+ 7]*s);
            unsigned w2 = f32x4_to_fp8(src[u*16+ 8]*s, src[u*16+ 9]*s, src[u*16+10]*s, src[u*16+11]*s);
            unsigned w3 = f32x4_to_fp8(src[u*16+12]*s, src[u*16+13]*s, src[u*16+14]*s, src[u*16+15]*s);
            *(uint4*)&outf8[((size_t)slice * M + grow) * 64 + cw] = make_uint4(w0, w1, w2, w3);
        }
    }
}

// Scatter-into-LDS aggregation. Block = (range r, slice s). acc[96][64] fp32.
// Edge loop: half-wave (32 lanes) per edge, 2 fp8 features/lane (ushort ->
// cvt_pk_f32_fp8), pair-unrolled (2 edges in flight per half-wave); LDS
// float atomics (stride-2 words -> 2 lanes/bank, free). Epilogue:
// relu(acc*d/32768 + self*d + b).  POOL: fused mean-pool partials (sorted
// batch -> <=4 graphs/range in LDS, else direct global atomic).
template <int S, bool POOL>
__global__ __launch_bounds__(256)
void gs_kernel(const unsigned char* __restrict__ xsb, const uint2* __restrict__ rng,
               const int* __restrict__ rangeBase, const float* __restrict__ dinv,
               const float* __restrict__ b, const int* __restrict__ batch,
               float* __restrict__ outv,     // POOL: sums; else h (bf16, cast)
               float* __restrict__ cntf, int N) {
    __shared__ float acc[NPR * 64];
    __shared__ float gsum[4][64];
    __shared__ float gcnt4[4];
    __shared__ int bloc[NPR];
    const int t = threadIdx.x;
    const int s = (S > 1) ? ((int)blockIdx.x & 1) : 0;
    const int r = (S > 1) ? ((int)blockIdx.x >> 1) : blockIdx.x;
    const unsigned char* xs = xsb + (size_t)s * N * 64;
    for (int i = t; i < NPR * 64; i += 256) acc[i] = 0.f;
    if (POOL) {
        for (int i = t; i < NPR; i += 256) {
            int node = r * NPR + i;
            bloc[i] = (node < N) ? batch[node] : -1;
        }
        if (t < 4) gcnt4[t] = 0.f;
        for (int i = t; i < 256; i += 256) ((float*)gsum)[i] = 0.f;
    }
    __syncthreads();
    const int ebase = rangeBase[r], eend = rangeBase[r + 1];
    const int w = t >> 6, lane = t & 63, sub = lane >> 5, k2 = (lane & 31) * 2;
    int e0 = ebase + w * 4 + sub * 2;
    for (; e0 + 1 < eend; e0 += 16) {
        uint2 ua = rng[e0], ub = rng[e0 + 1];
        int cla = (int)ua.x - r * NPR, clb = (int)ub.x - r * NPR;
        float ca = (float)(ua.y & 32767u), cb = (float)(ub.y & 32767u);
        unsigned pa = *(const unsigned short*)&xs[(size_t)(ua.y >> 15) * 64 + k2];
        unsigned pb = *(const unsigned short*)&xs[(size_t)(ub.y >> 15) * 64 + k2];
        v2f fa = __builtin_amdgcn_cvt_pk_f32_fp8((int)pa, false);
        v2f fb = __builtin_amdgcn_cvt_pk_f32_fp8((int)pb, false);
        atomicAdd(&acc[cla * 64 + k2],     fa[0] * ca);
        atomicAdd(&acc[cla * 64 + k2 + 1], fa[1] * ca);
        atomicAdd(&acc[clb * 64 + k2],     fb[0] * cb);
        atomicAdd(&acc[clb * 64 + k2 + 1], fb[1] * cb);
    }
    if (e0 < eend) {
        uint2 ua = rng[e0];
        int cla = (int)ua.x - r * NPR;
        float ca = (float)(ua.y & 32767u);
        unsigned pa = *(const unsigned short*)&xs[(size_t)(ua.y >> 15) * 64 + k2];
        v2f fa = __builtin_amdgcn_cvt_pk_f32_fp8((int)pa, false);
        atomicAdd(&acc[cla * 64 + k2],     fa[0] * ca);
        atomicAdd(&acc[cla * 64 + k2 + 1], fa[1] * ca);
    }
    __syncthreads();
    if (!POOL) {
        unsigned short* h = (unsigned short*)outv;
        for (int idx = t; idx < NPR * 32; idx += 256) {
            int ln = idx >> 5, kk2 = (idx & 31) * 2;
            int node = r * NPR + ln;
            if (node >= N) continue;
            float d = dinv[node], sa = d * (1.0f / 32768.0f);
            unsigned sp = *(const unsigned short*)&xs[(size_t)node * 64 + kk2];
            v2f sf = __builtin_amdgcn_cvt_pk_f32_fp8((int)sp, false);
            float o0 = fmaxf(acc[ln * 64 + kk2]     * sa + sf[0] * d + b[s * 64 + kk2], 0.f);
            float o1 = fmaxf(acc[ln * 64 + kk2 + 1] * sa + sf[1] * d + b[s * 64 + kk2 + 1], 0.f);
            unsigned pw = (unsigned)f2bf(o0) | ((unsigned)f2bf(o1) << 16);
            *(unsigned*)&h[(size_t)node * 128 + s * 64 + kk2] = pw;
        }
    } else {
        const int g0 = bloc[0];
        for (int idx = t; idx < NPR * 32; idx += 256) {
            int ln = idx >> 5, kk2 = (idx & 31) * 2;
            int node = r * NPR + ln;
            if (node >= N) continue;
            float d = dinv[node], sa = d * (1.0f / 32768.0f);
            unsigned sp = *(const unsigned short*)&xs[(size_t)node * 64 + kk2];
            v2f sf = __builtin_amdgcn_cvt_pk_f32_fp8((int)sp, false);
            float o0 = fmaxf(acc[ln * 64 + kk2]     * sa + sf[0] * d + b[kk2], 0.f);
            float o1 = fmaxf(acc[ln * 64 + kk2 + 1] * sa + sf[1] * d + b[kk2 + 1], 0.f);
            int g = bloc[ln] - g0;
            if (g < 4) {
                atomicAdd(&gsum[g][kk2],     o0);
                atomicAdd(&gsum[g][kk2 + 1], o1);
                if (kk2 == 0) atomicAdd(&gcnt4[g], 1.f);
            } else {
                atomicAdd(&outv[bloc[ln] * 64 + kk2],     o0);
                atomicAdd(&outv[bloc[ln] * 64 + kk2 + 1], o1);
                if (kk2 == 0) atomicAdd(&cntf[bloc[ln]], 1.f);
            }
        }
        __syncthreads();
        for (int idx = t; idx < 256; idx += 256) {
            int g = idx >> 6, f = idx & 63;
            if (gcnt4[g] > 0.f) atomicAdd(&outv[(g0 + g) * 64 + f], gsum[g][f]);
        }
        if (t < 4 && gcnt4[t] > 0.f) atomicAdd(&cntf[g0 + t], gcnt4[t]);
    }
}

// Head: one block per graph (see R12 notes).
__global__ void head_kernel(const float* __restrict__ sums, const float* __restrict__ cnt,
                            const float* __restrict__ fc1W, const float* __restrict__ fc1b,
                            const float* __restrict__ fc2W, const float* __restrict__ fc2b,
                            float* __restrict__ out) {
    __shared__ float x2s[64];
    __shared__ float hs[128];
    __shared__ float lg[2];
    const int g = blockIdx.x;
    const int t = threadIdx.x;
    if (t < 64) {
        float c = fmaxf(cnt[g], 1.f);
        x2s[t] = sums[g * 64 + t] / c;
    }
    __syncthreads();
    {
        float a = fc1b[t];
        #pragma unroll 8
        for (int j = 0; j < 64; ++j) a += x2s[j] * fc1W[j * 128 + t];
        hs[t] = fmaxf(a, 0.f);
    }
    __syncthreads();
    {
        int m = t >> 6, l = t & 63;
        float p = hs[l] * fc2W[l * 2 + m] + hs[l + 64] * fc2W[(l + 64) * 2 + m];
        #pragma unroll
        for (int off = 1; off < 64; off <<= 1) p += __shfl_xor(p, off);
        if (l == 0) lg[m] = p + fc2b[m];
    }
    __syncthreads();
    if (t == 0) {
        float l0 = lg[0], l1 = lg[1];
        float mx = fmaxf(l0, l1);
        float lse = mx + logf(expf(l0 - mx) + expf(l1 - mx));
        out[g * 2 + 0] = l0 - lse;
        out[g * 2 + 1] = l1 - lse;
    }
}

extern "C" void kernel_launch(void* const* d_in, const int* in_sizes, int n_in,
                              void* d_out, int out_size, void* d_ws, size_t ws_size,
                              hipStream_t stream) {
    const float* x      = (const float*)d_in[0];
    const int*   eidx   = (const int*)d_in[1];
    const float* ew     = (const float*)d_in[2];
    const int*   batch  = (const int*)d_in[3];
    const float* W1     = (const float*)d_in[4];
    const float* b1     = (const float*)d_in[5];
    const float* W2     = (const float*)d_in[6];
    const float* b2     = (const float*)d_in[7];
    const float* fc1W   = (const float*)d_in[8];
    const float* fc1b   = (const float*)d_in[9];
    const float* fc2W   = (const float*)d_in[10];
    const float* fc2b   = (const float*)d_in[11];
    float* out = (float*)d_out;

    const int N = in_sizes[3];          // 50000 nodes
    const int E = in_sizes[2];          // 1600000 edges
    const int G = 64;
    const int* rows = eidx;
    const int* cols = eidx + E;
    const int NRANGES = (N + NPR - 1) / NPR;   // 521 (must be <= RMAX)

    float* ws = (float*)d_ws;
    size_t off = 0;
    auto alloc = [&](size_t n) { float* p = ws + off; off += (n + 15) & ~(size_t)15; return p; };
    // --- zero-initialized region ---
    float* sums     = alloc(64 * 64);
    float* cntf     = alloc(64);
    int*   rangeCnt = (int*)alloc(RMAX);
    size_t zfloats = off;
    // --- rest ---
    float* dinv      = alloc(N);
    unsigned short* wt1 = (unsigned short*)alloc(128 * KP / 2 + 16);
    unsigned short* wt2 = (unsigned short*)alloc(64 * KP / 2 + 16);
    int*   rangeBase = (int*)alloc(RMAX + 16);
    int*   rangeCur  = (int*)alloc(RMAX);
    uint2* rng       = (uint2*)alloc((size_t)E * 2);      // [E] 8B records
    unsigned char* xwf8 = (unsigned char*)alloc((size_t)N * 32);  // [2][N][64] fp8 (L1) / [N][64] (L2)
    unsigned short* hbf = (unsigned short*)alloc((size_t)N * 64); // [N][128] bf16
    (void)ws_size;

    hipMemsetAsync(d_ws, 0, zfloats * sizeof(float), stream);

    // Weight prep + range-partitioned edge lists + dinv
    prepw_kernel<<<2, 256, 0, stream>>>(W1, W2, wt1, wt2);
    rangecnt_kernel<<<256, 256, 0, stream>>>(cols, rangeCnt, E, NRANGES);
    rangescan_kernel<<<1, 1024, 0, stream>>>(rangeCnt, rangeBase, rangeCur, NRANGES);
    partplace_kernel<<<256, 256, 0, stream>>>(rows, cols, ew, rangeCur, rng, E, NRANGES);
    degr_kernel<<<NRANGES, 256, 0, stream>>>(rng, rangeBase, dinv, N);

    // Layer 1: MFMA gemm (fp32 A) -> fp8 [2][N][64]; scatter-LDS -> h (bf16)
    gemm_mfma_kernel<128, true><<<(N + 63) / 64, 256, 0, stream>>>(x, wt1, dinv, xwf8, N);
    gs_kernel<2, false><<<NRANGES * 2, 256, 0, stream>>>(xwf8, rng, rangeBase, dinv, b1,
                                                         nullptr, (float*)hbf, nullptr, N);

    // Layer 2: MFMA gemm (bf16 A = h) -> fp8 [N][64]; scatter-LDS + fused pool
    gemm_mfma_kernel<64, false><<<(N + 63) / 64, 256, 0, stream>>>(hbf, wt2, dinv, xwf8, N);
    gs_kernel<1, true><<<NRANGES, 256, 0, stream>>>(xwf8, rng, rangeBase, dinv, b2,
                                                    batch, sums, cntf, N);

    // Head
    head_kernel<<<G, 128, 0, stream>>>(sums, cntf, fc1W, fc1b, fc2W, fc2b, out);
}

// Round 15
// 257.105 us; speedup vs baseline: 8.5947x; 8.5947x over previous
//
#include <hip/hip_runtime.h>
#include <hip/hip_bf16.h>

// ---------------------------------------------------------------------------
// GCN: h = relu(GCNConv(x,W1,b1)); x1 = relu(GCNConv(h,W2,b2));
//      x2 = meanpool(x1,batch); out = log_softmax(relu(x2@fc1+b)@fc2+b)
//
// R15: revert of R14 (LDS-atomic scatter was latency-serialized: 1262us at
// 3% VALU / 0.4% HBM -- LDS float atomics are NOT cheap at this density).
// Back to R13's measured-255us structure: two-phase CSR build + LDS-staged
// bucket gather + fp8 sliced tables + MFMA GEMMs. One micro-win: x1 stored
// bf16 (halves the x1 round-trip into pool).
// ---------------------------------------------------------------------------

#define CAP 64
#define OVFCAP 8192
#define MAXNR 6400   // max nodes per range (LDS histogram)
#define PCH 32       // chunks per range in the place pipeline
#define BSTR 68      // LDS bucket stride (words)
#define KP 136       // bf16 weight row stride (128 + 8 pad)

typedef float v2f  __attribute__((ext_vector_type(2)));
typedef float f32x4 __attribute__((ext_vector_type(4)));
typedef short bf16x8 __attribute__((ext_vector_type(8)));

__device__ inline unsigned short f2bf(float f) {   // fp32 -> bf16 RNE
    unsigned u = __float_as_uint(f);
    u += 0x7FFFu + ((u >> 16) & 1u);
    return (unsigned short)(u >> 16);
}
__device__ inline void fp8x4_to_f32(unsigned w, float* o) {
    v2f lo = __builtin_amdgcn_cvt_pk_f32_fp8((int)w, false);
    v2f hi = __builtin_amdgcn_cvt_pk_f32_fp8((int)w, true);
    o[0] = lo[0]; o[1] = lo[1]; o[2] = hi[0]; o[3] = hi[1];
}
__device__ inline unsigned f32x4_to_fp8(float a, float b, float c, float d) {
    int w = 0;
    w = __builtin_amdgcn_cvt_pk_fp8_f32(a, b, w, false);
    w = __builtin_amdgcn_cvt_pk_fp8_f32(c, d, w, true);
    return (unsigned)w;
}

// Weight prep: wt[c][k] (bf16, stride KP) = W[k][c].  Block 0 -> W1, 1 -> W2.
__global__ void prepw_kernel(const float* __restrict__ W1, const float* __restrict__ W2,
                             unsigned short* __restrict__ wt1, unsigned short* __restrict__ wt2) {
    int t = threadIdx.x;
    if (blockIdx.x == 0) {
        for (int i = t; i < 128 * 128; i += 256) {
            int c = i >> 7, k = i & 127;
            wt1[c * KP + k] = f2bf(W1[k * 128 + c]);
        }
    } else {
        for (int i = t; i < 64 * 128; i += 256) {
            int c = i >> 7, k = i & 127;
            wt2[c * KP + k] = f2bf(W2[k * 64 + c]);
        }
    }
}

// P1: partition edges into 8 per-range lists rng[r] of (col, row<<15|q15(ew)).
__global__ void part_kernel(const int* __restrict__ rows, const int* __restrict__ cols,
                            const float* __restrict__ ew, int* __restrict__ rangeCnt,
                            uint2* __restrict__ rng, int E, int NR, int RSEG) {
    __shared__ int hc[8];
    const int t = threadIdx.x;
    const int nb = gridDim.x;
    const int CS = (E + nb - 1) / nb;
    const int e0 = blockIdx.x * CS, e1 = min(e0 + CS, E);
    if (t < 8) hc[t] = 0;
    __syncthreads();
    for (int e = e0 + t; e < e1; e += 256) {
        int r = cols[e] / NR;
        atomicAdd(&hc[r], 1);
    }
    __syncthreads();
    if (t < 8) hc[t] = atomicAdd(&rangeCnt[t], hc[t]);   // hc becomes cursor base
    __syncthreads();
    for (int e = e0 + t; e < e1; e += 256) {
        int c = cols[e];
        int r = c / NR;
        int q = (int)(ew[e] * 32768.0f);
        if (q > 32767) q = 32767;
        unsigned rec = ((unsigned)rows[e] << 15) | (unsigned)q;
        int pos = atomicAdd(&hc[r], 1);
        if (pos < RSEG) rng[(size_t)r * RSEG + pos] = make_uint2((unsigned)c, rec);
    }
}

// P2a: per-(range,chunk) LDS histogram + q15 weight sum
__global__ __launch_bounds__(1024)
void hist2_kernel(const uint2* __restrict__ rng, const int* __restrict__ rangeCnt,
                  int* __restrict__ h2d, int* __restrict__ w2d, int NR, int RSEG) {
    __shared__ int hist[MAXNR];
    __shared__ int wsum[MAXNR];
    const int r = blockIdx.x & 7, j = blockIdx.x >> 3;
    const int t = threadIdx.x;
    const int M = min(rangeCnt[r], RSEG);
    const int CS = (M + PCH - 1) / PCH;
    const int e0 = j * CS, e1 = min(e0 + CS, M);
    for (int n = t; n < NR; n += 1024) { hist[n] = 0; wsum[n] = 0; }
    __syncthreads();
    const uint2* lst = rng + (size_t)r * RSEG;
    for (int k = e0 + t; k < e1; k += 1024) {
        unsigned c = lst[k].x - r * NR;
        atomicAdd(&hist[c], 1);
        atomicAdd(&wsum[c], (int)(lst[k].y & 32767u));
    }
    __syncthreads();
    int* dst = h2d + (size_t)(r * PCH + j) * NR;
    int* wdst = w2d + (size_t)(r * PCH + j) * NR;
    for (int n = t; n < NR; n += 1024) { dst[n] = hist[n]; wdst[n] = wsum[n]; }
}

// P2b: per-node exclusive prefix -> bases in h2d, total -> cnt, dinv from wsum.
__global__ void scan2_kernel(int* __restrict__ h2d, const int* __restrict__ w2d,
                             int* __restrict__ cnt, float* __restrict__ dinv, int NR, int N) {
    int n = blockIdx.x * 256 + threadIdx.x;
    if (n >= N) return;
    int r = n / NR, c = n - r * NR;
    int* col = h2d + (size_t)(r * PCH) * NR + c;
    const int* wcol = w2d + (size_t)(r * PCH) * NR + c;
    int run = 0;
    long long ws = 0;
    #pragma unroll 8
    for (int j = 0; j < PCH; ++j) {
        int v = col[(size_t)j * NR];
        col[(size_t)j * NR] = run;
        run += v;
        ws += wcol[(size_t)j * NR];
    }
    cnt[n] = run;
    dinv[n] = rsqrtf((float)ws * (1.0f / 32768.0f) + 1.0f);
}

// P2c: write slot records at deterministic positions (chunk base + LDS cursor).
__global__ __launch_bounds__(1024)
void place2_kernel(const uint2* __restrict__ rng, const int* __restrict__ rangeCnt,
                   const int* __restrict__ h2d, unsigned* __restrict__ slot,
                   int4* __restrict__ ovf, int* __restrict__ ovfcnt,
                   int NR, int RSEG) {
    __shared__ int cur[MAXNR];
    const int r = blockIdx.x & 7, j = blockIdx.x >> 3;
    const int t = threadIdx.x;
    const int M = min(rangeCnt[r], RSEG);
    const int CS = (M + PCH - 1) / PCH;
    const int e0 = j * CS, e1 = min(e0 + CS, M);
    const int* src = h2d + (size_t)(r * PCH + j) * NR;
    for (int n = t; n < NR; n += 1024) cur[n] = src[n];
    __syncthreads();
    const uint2* lst = rng + (size_t)r * RSEG;
    for (int k = e0 + t; k < e1; k += 1024) {
        uint2 u2 = lst[k];
        int pos = atomicAdd(&cur[u2.x - r * NR], 1);   // LDS cursor
        if (pos < CAP) {
            slot[(size_t)u2.x * CAP + pos] = u2.y;
        } else {
            int o = atomicAdd(ovfcnt, 1);
            if (o < OVFCAP)
                ovf[o] = make_int4((int)(u2.y >> 15), (int)u2.x, (int)(u2.y & 32767u), 0);
        }
    }
}

// Fallback for N too large for LDS histogram (not taken here).
__global__ void place_simple_kernel(const int* __restrict__ rows, const int* __restrict__ cols,
                                    const float* __restrict__ ew, int* __restrict__ cnt,
                                    unsigned* __restrict__ slot, int4* __restrict__ ovf,
                                    int* __restrict__ ovfcnt, int E) {
    int e = blockIdx.x * 256 + threadIdx.x;
    if (e >= E) return;
    int r = rows[e], c = cols[e];
    int q = (int)(ew[e] * 32768.0f);
    if (q > 32767) q = 32767;
    int pos = atomicAdd(&cnt[c], 1);
    if (pos < CAP) {
        slot[(size_t)c * CAP + pos] = ((unsigned)r << 15) | (unsigned)q;
    } else {
        int o = atomicAdd(ovfcnt, 1);
        if (o < OVFCAP) ovf[o] = make_int4(r, c, q, 0);
    }
}

// Fallback-path dinv (normal path computes dinv in scan2).
__global__ void degfin_kernel(const unsigned* __restrict__ slot, const int* __restrict__ cnt,
                              const int4* __restrict__ ovf, const int* __restrict__ ovfcnt,
                              float* __restrict__ dinv, int N) {
    const int w = threadIdx.x >> 6, lane = threadIdx.x & 63;
    const int i = blockIdx.x * 4 + w;
    if (i >= N) return;
    int mraw = cnt[i];
    int m = mraw > CAP ? CAP : mraw;
    float v = 0.f;
    if (lane < m) v = (float)(slot[(size_t)i * CAP + lane] & 32767u);
    if (mraw > CAP) {
        int oc = *ovfcnt; if (oc > OVFCAP) oc = OVFCAP;
        for (int k = lane; k < oc; k += 64)
            if (ovf[k].y == i) v += (float)ovf[k].z;
    }
    #pragma unroll
    for (int off = 1; off < 64; off <<= 1) v += __shfl_xor(v, off);
    if (lane == 0) dinv[i] = rsqrtf(v * (1.0f / 32768.0f) + 1.0f);
}

// MFMA bf16 GEMM -> fp8 sliced table. outf8[slice][M][64] = (A@W)*dinv[row].
template <int BN, bool AF32>
__global__ __launch_bounds__(256)
void gemm_mfma_kernel(const void* __restrict__ Av, const unsigned short* __restrict__ wt,
                      const float* __restrict__ dinv, unsigned char* __restrict__ outf8,
                      int M) {
    constexpr int CT = BN / 16;
    constexpr int EPS = BN + 4;
    __shared__ unsigned short wl[BN * KP];
    __shared__ float ep[4][16 * EPS];
    const int t = threadIdx.x;
    for (int i = t; i < BN * KP / 8; i += 256)
        ((uint4*)wl)[i] = ((const uint4*)wt)[i];
    __syncthreads();
    const int w = t >> 6, lane = t & 63;
    const int n16 = lane & 15, q = lane >> 4;
    const int rowBase = blockIdx.x * 64 + w * 16;
    int arow = rowBase + n16; if (arow >= M) arow = M - 1;
    f32x4 acc[CT];
    #pragma unroll
    for (int ct = 0; ct < CT; ++ct) acc[ct] = (f32x4){0.f, 0.f, 0.f, 0.f};
    #pragma unroll
    for (int kt = 0; kt < 4; ++kt) {
        bf16x8 af;
        if (AF32) {
            const float* ap = (const float*)Av + (size_t)arow * 128 + kt * 32 + q * 8;
            float4 a0 = *(const float4*)ap;
            float4 a1 = *(const float4*)(ap + 4);
            af[0] = (short)f2bf(a0.x); af[1] = (short)f2bf(a0.y);
            af[2] = (short)f2bf(a0.z); af[3] = (short)f2bf(a0.w);
            af[4] = (short)f2bf(a1.x); af[5] = (short)f2bf(a1.y);
            af[6] = (short)f2bf(a1.z); af[7] = (short)f2bf(a1.w);
        } else {
            af = *(const bf16x8*)((const unsigned short*)Av + (size_t)arow * 128 + kt * 32 + q * 8);
        }
        #pragma unroll
        for (int ct = 0; ct < CT; ++ct) {
            bf16x8 bfr = *(const bf16x8*)&wl[(ct * 16 + n16) * KP + kt * 32 + q * 8];
            acc[ct] = __builtin_amdgcn_mfma_f32_16x16x32_bf16(af, bfr, acc[ct], 0, 0, 0);
        }
    }
    #pragma unroll
    for (int ct = 0; ct < CT; ++ct)
        #pragma unroll
        for (int r = 0; r < 4; ++r)
            ep[w][(q * 4 + r) * EPS + ct * 16 + n16] = acc[ct][r];
    __syncthreads();
    const int lr = lane & 15;
    const int cc = (lane >> 4) * (BN / 4);
    int grow = rowBase + lr;
    if (grow < M) {
        float s = dinv[grow];
        const float* src = &ep[w][lr * EPS + cc];
        #pragma unroll
        for (int u = 0; u < BN / 64; ++u) {
            int col0 = cc + u * 16;
            int slice = col0 >> 6, cw = col0 & 63;
            unsigned w0 = f32x4_to_fp8(src[u*16+ 0]*s, src[u*16+ 1]*s, src[u*16+ 2]*s, src[u*16+ 3]*s);
            unsigned w1 = f32x4_to_fp8(src[u*16+ 4]*s, src[u*16+ 5]*s, src[u*16+ 6]*s, src[u*16+ 7]*s);
            unsigned w2 = f32x4_to_fp8(src[u*16+ 8]*s, src[u*16+ 9]*s, src[u*16+10]*s, src[u*16+11]*s);
            unsigned w3 = f32x4_to_fp8(src[u*16+12]*s, src[u*16+13]*s, src[u*16+14]*s, src[u*16+15]*s);
            *(uint4*)&outf8[((size_t)slice * M + grow) * 64 + cw] = make_uint4(w0, w1, w2, w3);
        }
    }
}

// Sliced fp8 aggregation with LDS-staged buckets (R10/R11 structure).
// OB: output bf16 ([N][F] bf16) vs fp32.
template <int F, int S, bool OB>
__global__ void gather_kernel(const unsigned char* __restrict__ xsb,
                              const unsigned* __restrict__ slot,
                              const int* __restrict__ cnt, const float* __restrict__ dinv,
                              const float* __restrict__ b, const int4* __restrict__ ovf,
                              const int* __restrict__ ovfcnt, void* __restrict__ outv, int N) {
    constexpr int EPN = 4;           // edges in flight per node
    __shared__ unsigned sbkt[16 * BSTR];
    const int slice = (S > 1) ? ((int)blockIdx.x % S) : 0;
    const int grp = (S > 1) ? ((int)blockIdx.x / S) : blockIdx.x;
    const int t = threadIdx.x;
    const int node0 = grp * 16;
    {   // stage 16 buckets (coalesced): thread t -> bucket t/16, chunk t%16
        int ndl = t >> 4, part = t & 15;
        int snode = node0 + ndl; if (snode >= N) snode = N - 1;
        *(uint4*)&sbkt[ndl * BSTR + part * 4] =
            *(const uint4*)&slot[(size_t)snode * CAP + part * 4];
    }
    __syncthreads();
    const int w = t >> 6, lane = t & 63;
    const int cg = lane & 3;
    const int e  = (lane >> 2) & 3;
    const int nd = lane >> 4;
    const int ndl = w * 4 + nd;          // local node 0..15
    const int i = node0 + ndl;
    const bool iv = (i < N);
    const int ic = iv ? i : 0;
    const uint4* xs4 = (const uint4*)(xsb + (size_t)slice * N * 64);
    int mraw = iv ? cnt[ic] : 0;
    int m = mraw > CAP ? CAP : mraw;
    const unsigned* lb = &sbkt[ndl * BSTR];
    float acc[16] = {};
    int j = e;
    for (; j + EPN < m; j += 2 * EPN) {
        unsigned u0 = lb[j], u1 = lb[j + EPN];
        float c0 = (float)(u0 & 32767u), c1 = (float)(u1 & 32767u);
        uint4 a0 = xs4[(size_t)(u0 >> 15) * 4 + cg];
        uint4 a1 = xs4[(size_t)(u1 >> 15) * 4 + cg];
        float f0[16], f1[16];
        fp8x4_to_f32(a0.x, f0 + 0);  fp8x4_to_f32(a0.y, f0 + 4);
        fp8x4_to_f32(a0.z, f0 + 8);  fp8x4_to_f32(a0.w, f0 + 12);
        fp8x4_to_f32(a1.x, f1 + 0);  fp8x4_to_f32(a1.y, f1 + 4);
        fp8x4_to_f32(a1.z, f1 + 8);  fp8x4_to_f32(a1.w, f1 + 12);
        #pragma unroll
        for (int k = 0; k < 16; ++k) acc[k] += f0[k] * c0 + f1[k] * c1;
    }
    if (j < m) {
        unsigned u = lb[j];
        float c = (float)(u & 32767u);
        uint4 a = xs4[(size_t)(u >> 15) * 4 + cg];
        float f[16];
        fp8x4_to_f32(a.x, f + 0);  fp8x4_to_f32(a.y, f + 4);
        fp8x4_to_f32(a.z, f + 8);  fp8x4_to_f32(a.w, f + 12);
        #pragma unroll
        for (int k = 0; k < 16; ++k) acc[k] += f[k] * c;
    }
    if (mraw > CAP) {                     // inline overflow (normally skipped)
        int oc = *ovfcnt; if (oc > OVFCAP) oc = OVFCAP;
        for (int k = e; k < oc; k += EPN) {
            int4 r4 = ovf[k];
            if (r4.y == i) {
                float c = (float)r4.z;
                uint4 a = xs4[(size_t)r4.x * 4 + cg];
                float f[16];
                fp8x4_to_f32(a.x, f + 0);  fp8x4_to_f32(a.y, f + 4);
                fp8x4_to_f32(a.z, f + 8);  fp8x4_to_f32(a.w, f + 12);
                #pragma unroll
                for (int kk = 0; kk < 16; ++kk) acc[kk] += f[kk] * c;
            }
        }
    }
    #pragma unroll
    for (int k = 0; k < 16; ++k) {
        acc[k] += __shfl_xor(acc[k], 4);
        acc[k] += __shfl_xor(acc[k], 8);
    }
    if (e == 0 && iv) {
        float d = dinv[i];
        float sa = d * (1.0f / 32768.0f);
        uint4 sv = xs4[(size_t)i * 4 + cg];
        float sf[16];
        fp8x4_to_f32(sv.x, sf + 0);  fp8x4_to_f32(sv.y, sf + 4);
        fp8x4_to_f32(sv.z, sf + 8);  fp8x4_to_f32(sv.w, sf + 12);
        const float* bb = &b[slice * 64 + cg * 16];
        float o[16];
        #pragma unroll
        for (int k = 0; k < 16; ++k)
            o[k] = fmaxf(acc[k] * sa + sf[k] * d + bb[k], 0.f);
        if (OB) {
            unsigned short* dst = (unsigned short*)outv + (size_t)i * F + slice * 64 + cg * 16;
            unsigned pw[8];
            #pragma unroll
            for (int k = 0; k < 8; ++k)
                pw[k] = (unsigned)f2bf(o[2 * k]) | ((unsigned)f2bf(o[2 * k + 1]) << 16);
            *(uint4*)&dst[0] = make_uint4(pw[0], pw[1], pw[2], pw[3]);
            *(uint4*)&dst[8] = make_uint4(pw[4], pw[5], pw[6], pw[7]);
        } else {
            float* dst = (float*)outv + (size_t)i * F + slice * 64 + cg * 16;
            *(float4*)&dst[0]  = make_float4(o[0], o[1], o[2], o[3]);
            *(float4*)&dst[4]  = make_float4(o[4], o[5], o[6], o[7]);
            *(float4*)&dst[8]  = make_float4(o[8], o[9], o[10], o[11]);
            *(float4*)&dst[12] = make_float4(o[12], o[13], o[14], o[15]);
        }
    }
}

// sums[batch[n]] += x1[n] (bf16 [N][64]); cnt[batch[n]] += 1.
__global__ void pool_kernel(const unsigned short* __restrict__ x1, const int* __restrict__ batch,
                            float* __restrict__ sums, float* __restrict__ cnt, int N) {
    constexpr int QG = 16, S = 16, ITER = 16;
    int t = threadIdx.x;
    int q = t % QG, s = t / QG;
    int n0 = blockIdx.x * (S * ITER) + s * ITER;
    float4 acc = make_float4(0.f, 0.f, 0.f, 0.f);
    float cacc = 0.f;
    int gcur = -1;
    for (int i = 0; i < ITER; ++i) {
        int n = n0 + i;
        if (n >= N) break;
        int gid = batch[n];
        if (gid != gcur) {
            if (gcur >= 0) {
                float* dst = &sums[gcur * 64 + q * 4];
                atomicAdd(dst + 0, acc.x);
                atomicAdd(dst + 1, acc.y);
                atomicAdd(dst + 2, acc.z);
                atomicAdd(dst + 3, acc.w);
                if (q == 0) atomicAdd(&cnt[gcur], cacc);
            }
            gcur = gid;
            acc = make_float4(0.f, 0.f, 0.f, 0.f);
            cacc = 0.f;
        }
        uint2 p = *(const uint2*)&x1[(size_t)n * 64 + q * 4];
        acc.x += __uint_as_float(p.x << 16);
        acc.y += __uint_as_float(p.x & 0xFFFF0000u);
        acc.z += __uint_as_float(p.y << 16);
        acc.w += __uint_as_float(p.y & 0xFFFF0000u);
        if (q == 0) cacc += 1.f;
    }
    if (gcur >= 0) {
        float* dst = &sums[gcur * 64 + q * 4];
        atomicAdd(dst + 0, acc.x);
        atomicAdd(dst + 1, acc.y);
        atomicAdd(dst + 2, acc.z);
        atomicAdd(dst + 3, acc.w);
        if (q == 0) atomicAdd(&cnt[gcur], cacc);
    }
}

// Head: one block per graph (see R12 notes).
__global__ void head_kernel(const float* __restrict__ sums, const float* __restrict__ cnt,
                            const float* __restrict__ fc1W, const float* __restrict__ fc1b,
                            const float* __restrict__ fc2W, const float* __restrict__ fc2b,
                            float* __restrict__ out) {
    __shared__ float x2s[64];
    __shared__ float hs[128];
    __shared__ float lg[2];
    const int g = blockIdx.x;
    const int t = threadIdx.x;
    if (t < 64) {
        float c = fmaxf(cnt[g], 1.f);
        x2s[t] = sums[g * 64 + t] / c;
    }
    __syncthreads();
    {
        float a = fc1b[t];
        #pragma unroll 8
        for (int j = 0; j < 64; ++j) a += x2s[j] * fc1W[j * 128 + t];
        hs[t] = fmaxf(a, 0.f);
    }
    __syncthreads();
    {
        int m = t >> 6, l = t & 63;
        float p = hs[l] * fc2W[l * 2 + m] + hs[l + 64] * fc2W[(l + 64) * 2 + m];
        #pragma unroll
        for (int off = 1; off < 64; off <<= 1) p += __shfl_xor(p, off);
        if (l == 0) lg[m] = p + fc2b[m];
    }
    __syncthreads();
    if (t == 0) {
        float l0 = lg[0], l1 = lg[1];
        float mx = fmaxf(l0, l1);
        float lse = mx + logf(expf(l0 - mx) + expf(l1 - mx));
        out[g * 2 + 0] = l0 - lse;
        out[g * 2 + 1] = l1 - lse;
    }
}

extern "C" void kernel_launch(void* const* d_in, const int* in_sizes, int n_in,
                              void* d_out, int out_size, void* d_ws, size_t ws_size,
                              hipStream_t stream) {
    const float* x      = (const float*)d_in[0];
    const int*   eidx   = (const int*)d_in[1];
    const float* ew     = (const float*)d_in[2];
    const int*   batch  = (const int*)d_in[3];
    const float* W1     = (const float*)d_in[4];
    const float* b1     = (const float*)d_in[5];
    const float* W2     = (const float*)d_in[6];
    const float* b2     = (const float*)d_in[7];
    const float* fc1W   = (const float*)d_in[8];
    const float* fc1b   = (const float*)d_in[9];
    const float* fc2W   = (const float*)d_in[10];
    const float* fc2b   = (const float*)d_in[11];
    float* out = (float*)d_out;

    const int N = in_sizes[3];          // 50000 nodes
    const int E = in_sizes[2];          // 1600000 edges
    const int G = 64;
    const int* rows = eidx;
    const int* cols = eidx + E;
    const int NR = (N + 7) / 8;
    const int RSEG = E / 8 + 32768;

    float* ws = (float*)d_ws;
    size_t off = 0;
    auto alloc = [&](size_t n) { float* p = ws + off; off += (n + 15) & ~(size_t)15; return p; };
    // --- zero-initialized region ---
    float*    sums     = alloc(64 * 64);
    float*    cntf     = alloc(16);
    int*      ovfcnt   = (int*)alloc(16);
    int*      rangeCnt = (int*)alloc(16);
    int*      cnt      = (int*)alloc(N);          // zeroed for fallback path only
    size_t zfloats = off;
    // --- rest ---
    float*    dinv   = alloc(N);
    unsigned short* wt1 = (unsigned short*)alloc(128 * KP / 2 + 16);
    unsigned short* wt2 = (unsigned short*)alloc(64 * KP / 2 + 16);
    unsigned* slot   = (unsigned*)alloc((size_t)N * CAP);
    int4*     ovf    = (int4*)alloc((size_t)OVFCAP * 4);
    float*    bufA   = alloc((size_t)N * 128);   // h2d+w2d | xw1f8 | xw2f8 + x1
    float*    bufB   = alloc((size_t)N * 128);   // rng | h(bf16)
    int*            h2d   = (int*)bufA;                        // 8*PCH*NR ints
    int*            w2d   = h2d + (size_t)8 * PCH * NR;        // 8*PCH*NR ints
    unsigned char*  xw1f8 = (unsigned char*)bufA;              // [2][N][64] fp8
    unsigned char*  xw2f8 = (unsigned char*)bufA;              // [1][N][64] fp8
    unsigned short* x1bf  = (unsigned short*)(bufA + (size_t)N * 32); // [N][64] bf16
    uint2*          rng   = (uint2*)bufB;                      // 8*RSEG uint2, dead before h
    unsigned short* hbf   = (unsigned short*)bufB;             // [N][128] bf16
    (void)ws_size;

    hipMemsetAsync(d_ws, 0, zfloats * sizeof(float), stream);

    // Weight prep (independent of CSR build)
    prepw_kernel<<<2, 256, 0, stream>>>(W1, W2, wt1, wt2);

    // CSR build: partition -> histogram(+wsum) -> prefix(+dinv) -> place
    if (NR <= MAXNR) {
        part_kernel<<<256, 256, 0, stream>>>(rows, cols, ew, rangeCnt, rng, E, NR, RSEG);
        hist2_kernel<<<8 * PCH, 1024, 0, stream>>>(rng, rangeCnt, h2d, w2d, NR, RSEG);
        scan2_kernel<<<(N + 255) / 256, 256, 0, stream>>>(h2d, w2d, cnt, dinv, NR, N);
        place2_kernel<<<8 * PCH, 1024, 0, stream>>>(rng, rangeCnt, h2d, slot, ovf, ovfcnt, NR, RSEG);
    } else {
        place_simple_kernel<<<(E + 255) / 256, 256, 0, stream>>>(rows, cols, ew, cnt, slot, ovf, ovfcnt, E);
        degfin_kernel<<<(N + 3) / 4, 256, 0, stream>>>(slot, cnt, ovf, ovfcnt, dinv, N);
    }

    // Layer 1: MFMA gemm (fp32 A) -> fp8 table (2 slices); gather -> h (bf16)
    gemm_mfma_kernel<128, true><<<(N + 63) / 64, 256, 0, stream>>>(x, wt1, dinv, xw1f8, N);
    gather_kernel<128, 2, true><<<((N + 15) / 16) * 2, 256, 0, stream>>>(xw1f8, slot, cnt, dinv, b1, ovf, ovfcnt, hbf, N);

    // Layer 2: MFMA gemm (bf16 A = h) -> fp8 table (1 slice); gather -> x1 (bf16)
    gemm_mfma_kernel<64, false><<<(N + 63) / 64, 256, 0, stream>>>(hbf, wt2, dinv, xw2f8, N);
    gather_kernel<64, 1, true><<<(N + 15) / 16, 256, 0, stream>>>(xw2f8, slot, cnt, dinv, b2, ovf, ovfcnt, x1bf, N);

    // Mean-pool + head
    pool_kernel<<<(N + 255) / 256, 256, 0, stream>>>(x1bf, batch, sums, cntf, N);
    head_kernel<<<G, 128, 0, stream>>>(sums, cntf, fc1W, fc1b, fc2W, fc2b, out);
}